// Round 3
// baseline (53.112 us; speedup 1.0000x reference)
//
#include <hip/hip_runtime.h>
#include <math.h>

#define H_BINS 61
#define HB2 (H_BINS * H_BINS)      // 3721
#define NPIX 22500                 // 150*150
#define NIMG 64
#define CHUNKS 12                  // 22500 / 12 = 1875 exactly
#define PIX_PER_CHUNK (NPIX / CHUNKS)
#define OUT_ELEMS (NIMG * 3 * HB2) // 714432

// EPS from reference, as float32
#define EPSF 2.2204e-16f
// EPS_BIN/2 = 6.4/61/2 computed in double, cast to f32 (matches jnp scalar cast)
#define HALFW ((float)(6.4 / 61.0 / 2.0))

// A[h] = -3.2f + h * delta, delta = (3.0951f - (-3.2f)) / 60.0f, all f32 rn ops
// (mirrors jnp.linspace in float32; rn intrinsics block FMA contraction)
__device__ __forceinline__ float bin_center(int h) {
    const float delta = __fdiv_rn(__fsub_rn(3.0951f, -3.2f), 60.0f);
    return __fadd_rn(-3.2f, __fmul_rn((float)h, delta));
}

// Find all bins h with |t - A[h]| <= HALFW (exact f32 predicate).
// Disjoint intervals => normally 0 or 1 match; we allow 2 for safety.
__device__ __forceinline__ int find_bins(float t, int* out) {
    const float inv_delta = 60.0f / 6.2951f;  // only used for the index ESTIMATE
    int h0 = (int)floorf(__fmul_rn(__fadd_rn(t, 3.2f), inv_delta) + 0.5f);
    int c = 0;
    #pragma unroll
    for (int dh = -1; dh <= 1; ++dh) {
        int h = h0 + dh;
        if (h < 0 || h >= H_BINS) continue;
        float a = bin_center(h);
        if (fabsf(__fsub_rn(t, a)) <= HALFW) {
            if (c < 2) out[c] = h;
            ++c;
        }
    }
    return c < 2 ? c : 2;
}

__global__ __launch_bounds__(256) void zero_kernel(float4* __restrict__ out, int n4) {
    int i = blockIdx.x * 256 + threadIdx.x;
    if (i < n4) out[i] = make_float4(0.f, 0.f, 0.f, 0.f);
}

// One block = one (image, pixel-chunk); computes ALL 3 channel-pairs so the
// 3 logf per pixel are shared. LDS = 3 x 61x61 f32 (44.6 KB -> 3 blocks/CU;
// 512 thr = 8 waves -> 24 waves/CU occupancy cap).
__global__ __launch_bounds__(512) void hist_kernel(const float* __restrict__ X,
                                                   float* __restrict__ out) {
    __shared__ float hist[3][HB2];
    const int chunk = blockIdx.x % CHUNKS;
    const int b     = blockIdx.x / CHUNKS;

    float* hflat = &hist[0][0];
    for (int i = threadIdx.x; i < 3 * HB2; i += 512) hflat[i] = 0.0f;
    __syncthreads();

    const float* Xb = X + (size_t)b * 3 * NPIX;
    const int n0 = chunk * PIX_PER_CHUNK;
    const int n1 = n0 + PIX_PER_CHUNK;

    for (int n = n0 + threadIdx.x; n < n1; n += 512) {
        float r  = Xb[n];
        float g  = Xb[NPIX + n];
        float bl = Xb[2 * NPIX + n];

        // Iy = sqrt(r*r + g*g + b*b), f32 rn ops, sum order ((rr+gg)+bb)
        float iy = __fsqrt_rn(__fadd_rn(
            __fadd_rn(__fmul_rn(r, r), __fmul_rn(g, g)), __fmul_rn(bl, bl)));

        // logs computed ONCE per pixel, shared by all 3 pairs (identical ops
        // to reference: logf(|x| + EPS) in f32)
        float l0 = logf(__fadd_rn(fabsf(r),  EPSF));
        float l1 = logf(__fadd_rn(fabsf(g),  EPSF));
        float l2 = logf(__fadd_rn(fabsf(bl), EPSF));

        // pairs: (i,u,v) = (0,1,2), (1,0,2), (2,0,1)
        float iu[3], iv[3];
        iu[0] = __fsub_rn(l0, l1);  iv[0] = __fsub_rn(l0, l2);
        iu[1] = __fsub_rn(l1, l0);  iv[1] = __fsub_rn(l1, l2);
        iu[2] = __fsub_rn(l2, l0);  iv[2] = __fsub_rn(l2, l1);

        #pragma unroll
        for (int p = 0; p < 3; ++p) {
            int bu[2], bv[2];
            int nu = find_bins(iu[p], bu);
            if (nu == 0) continue;
            int nv = find_bins(iv[p], bv);
            if (nv == 0) continue;
            for (int a = 0; a < nu; ++a)
                for (int c = 0; c < nv; ++c)
                    unsafeAtomicAdd(&hist[p][bu[a] * H_BINS + bv[c]], iy);  // native ds_add_f32
        }
    }
    __syncthreads();

    float* ob = out + (size_t)b * 3 * HB2;
    for (int i = threadIdx.x; i < 3 * HB2; i += 512) {
        float v = hflat[i];
        if (v != 0.0f) unsafeAtomicAdd(&ob[i], v);  // native global_atomic_add_f32
    }
}

__global__ __launch_bounds__(256) void finalize_kernel(float* __restrict__ out,
                                                       const float* __restrict__ C) {
    int idx = blockIdx.x * 256 + threadIdx.x;
    if (idx >= OUT_ELEMS) return;
    int ch = (idx / HB2) % 3;
    float scale = __fdiv_rn(C[ch], 22500.0f);   // C[i]/N in f32, as reference
    out[idx] = __fmul_rn(__fsqrt_rn(out[idx]), scale);
}

extern "C" void kernel_launch(void* const* d_in, const int* in_sizes, int n_in,
                              void* d_out, int out_size, void* d_ws, size_t ws_size,
                              hipStream_t stream) {
    const float* X = (const float*)d_in[0];
    const float* C = (const float*)d_in[1];
    float* out = (float*)d_out;

    // d_out is our accumulator: zero it ourselves (runtime fill kernel is slow)
    int n4 = OUT_ELEMS / 4;  // 714432 divisible by 4
    zero_kernel<<<(n4 + 255) / 256, 256, 0, stream>>>((float4*)out, n4);

    hist_kernel<<<NIMG * CHUNKS, 512, 0, stream>>>(X, out);

    finalize_kernel<<<(OUT_ELEMS + 255) / 256, 256, 0, stream>>>(out, C);
}

// Round 4
// 45.046 us; speedup vs baseline: 1.1791x; 1.1791x over previous
//
#include <hip/hip_runtime.h>
#include <math.h>

#define H_BINS 61
#define HB2 (H_BINS * H_BINS)      // 3721
#define SLOTS (3 * HB2)            // 11163 floats per (image,chunk) partial
#define NPIX 22500                 // 150*150
#define NIMG 64
#define OUT_ELEMS (NIMG * SLOTS)   // 714432

// EPS from reference, as float32
#define EPSF 2.2204e-16f
// EPS_BIN/2 = 6.4/61/2 computed in double, cast to f32 (matches jnp scalar cast)
#define HALFW ((float)(6.4 / 61.0 / 2.0))

// A[h] = -3.2f + h * delta, delta = (3.0951f - (-3.2f)) / 60.0f, all f32 rn ops
// (mirrors jnp.linspace in float32; rn intrinsics block FMA contraction)
__device__ __forceinline__ float bin_center(int h) {
    const float delta = __fdiv_rn(__fsub_rn(3.0951f, -3.2f), 60.0f);
    return __fadd_rn(-3.2f, __fmul_rn((float)h, delta));
}

// Find all bins h with |t - A[h]| <= HALFW (exact f32 predicate).
// Disjoint intervals => normally 0 or 1 match; we allow 2 for safety.
__device__ __forceinline__ int find_bins(float t, int* out) {
    const float inv_delta = 60.0f / 6.2951f;  // only used for the index ESTIMATE
    int h0 = (int)floorf(__fmul_rn(__fadd_rn(t, 3.2f), inv_delta) + 0.5f);
    int c = 0;
    #pragma unroll
    for (int dh = -1; dh <= 1; ++dh) {
        int h = h0 + dh;
        if (h < 0 || h >= H_BINS) continue;
        float a = bin_center(h);
        if (fabsf(__fsub_rn(t, a)) <= HALFW) {
            if (c < 2) out[c] = h;
            ++c;
        }
    }
    return c < 2 ? c : 2;
}

// One block = one (image, pixel-chunk), all 3 channel-pairs (logs shared).
// LDS = 3 x 61x61 f32 (44.6 KB -> 3 blocks/CU; 512 thr -> 24 waves/CU cap).
// FLUSH_WS: plain coalesced stores of the full partial to ws[blockIdx]
// (no global atomics). Fallback (!FLUSH_WS): device atomics into dst.
template <bool FLUSH_WS>
__global__ __launch_bounds__(512) void hist_kernel(const float* __restrict__ X,
                                                   float* __restrict__ dst,
                                                   int nchunks, int ppc) {
    __shared__ float hist[3][HB2];
    const int chunk = blockIdx.x % nchunks;
    const int b     = blockIdx.x / nchunks;

    float* hflat = &hist[0][0];
    for (int i = threadIdx.x; i < SLOTS; i += 512) hflat[i] = 0.0f;
    __syncthreads();

    const float* Xb = X + (size_t)b * 3 * NPIX;
    const int n0 = chunk * ppc;
    int n1 = n0 + ppc; if (n1 > NPIX) n1 = NPIX;

    for (int n = n0 + threadIdx.x; n < n1; n += 512) {
        float r  = Xb[n];
        float g  = Xb[NPIX + n];
        float bl = Xb[2 * NPIX + n];

        // Iy = sqrt(r*r + g*g + b*b), f32 rn ops, sum order ((rr+gg)+bb)
        float iy = __fsqrt_rn(__fadd_rn(
            __fadd_rn(__fmul_rn(r, r), __fmul_rn(g, g)), __fmul_rn(bl, bl)));

        // logs once per pixel, shared by all 3 pairs: logf(|x| + EPS) in f32
        float l0 = logf(__fadd_rn(fabsf(r),  EPSF));
        float l1 = logf(__fadd_rn(fabsf(g),  EPSF));
        float l2 = logf(__fadd_rn(fabsf(bl), EPSF));

        // pairs: (i,u,v) = (0,1,2), (1,0,2), (2,0,1)
        float iu[3], iv[3];
        iu[0] = __fsub_rn(l0, l1);  iv[0] = __fsub_rn(l0, l2);
        iu[1] = __fsub_rn(l1, l0);  iv[1] = __fsub_rn(l1, l2);
        iu[2] = __fsub_rn(l2, l0);  iv[2] = __fsub_rn(l2, l1);

        #pragma unroll
        for (int p = 0; p < 3; ++p) {
            int bu[2], bv[2];
            int nu = find_bins(iu[p], bu);
            if (nu == 0) continue;
            int nv = find_bins(iv[p], bv);
            if (nv == 0) continue;
            for (int a = 0; a < nu; ++a)
                for (int c = 0; c < nv; ++c)
                    unsafeAtomicAdd(&hist[p][bu[a] * H_BINS + bv[c]], iy);  // native ds_add_f32
        }
    }
    __syncthreads();

    if (FLUSH_WS) {
        // private partial: plain coalesced streaming stores, zero atomics
        float* wsdst = dst + (size_t)blockIdx.x * SLOTS;
        for (int i = threadIdx.x; i < SLOTS; i += 512) wsdst[i] = hflat[i];
    } else {
        float* ob = dst + (size_t)b * SLOTS;
        for (int i = threadIdx.x; i < SLOTS; i += 512) {
            float v = hflat[i];
            if (v != 0.0f) unsafeAtomicAdd(&ob[i], v);
        }
    }
}

// out[idx] = sqrt(sum over chunk-partials) * C[ch] / N   (fused finalize)
__global__ __launch_bounds__(256) void reduce_kernel(const float* __restrict__ ws,
                                                     const float* __restrict__ C,
                                                     float* __restrict__ out,
                                                     int nchunks) {
    int idx = blockIdx.x * 256 + threadIdx.x;
    if (idx >= OUT_ELEMS) return;
    int b  = idx / SLOTS;
    int j  = idx % SLOTS;
    int ch = j / HB2;
    const float* base = ws + (size_t)b * nchunks * SLOTS + j;
    float s = 0.0f;
    for (int c = 0; c < nchunks; ++c) s = __fadd_rn(s, base[(size_t)c * SLOTS]);
    float scale = __fdiv_rn(C[ch], 22500.0f);   // C[i]/N in f32, as reference
    out[idx] = __fmul_rn(__fsqrt_rn(s), scale);
}

__global__ __launch_bounds__(256) void zero_kernel(float4* __restrict__ out, int n4) {
    int i = blockIdx.x * 256 + threadIdx.x;
    if (i < n4) out[i] = make_float4(0.f, 0.f, 0.f, 0.f);
}

__global__ __launch_bounds__(256) void finalize_kernel(float* __restrict__ out,
                                                       const float* __restrict__ C) {
    int idx = blockIdx.x * 256 + threadIdx.x;
    if (idx >= OUT_ELEMS) return;
    int ch = (idx / HB2) % 3;
    float scale = __fdiv_rn(C[ch], 22500.0f);
    out[idx] = __fmul_rn(__fsqrt_rn(out[idx]), scale);
}

extern "C" void kernel_launch(void* const* d_in, const int* in_sizes, int n_in,
                              void* d_out, int out_size, void* d_ws, size_t ws_size,
                              hipStream_t stream) {
    const float* X = (const float*)d_in[0];
    const float* C = (const float*)d_in[1];
    float* out = (float*)d_out;
    float* ws  = (float*)d_ws;

    // Pick chunk count by workspace fit (deterministic: ws_size is constant).
    // CH=12 -> 768 blocks = 3/CU (best), needs 34.3 MB ws.
    const int cands[5] = {12, 8, 4, 2, 1};
    int CH = 0;
    for (int k = 0; k < 5; ++k) {
        size_t need = (size_t)NIMG * cands[k] * SLOTS * sizeof(float);
        if (ws_size >= need) { CH = cands[k]; break; }
    }

    if (CH > 0) {
        int ppc = (NPIX + CH - 1) / CH;
        hist_kernel<true><<<NIMG * CH, 512, 0, stream>>>(X, ws, CH, ppc);
        reduce_kernel<<<(OUT_ELEMS + 255) / 256, 256, 0, stream>>>(ws, C, out, CH);
    } else {
        // tiny-ws fallback: accumulate into out with device atomics (R3 path)
        int n4 = OUT_ELEMS / 4;
        zero_kernel<<<(n4 + 255) / 256, 256, 0, stream>>>((float4*)out, n4);
        hist_kernel<false><<<NIMG * 12, 512, 0, stream>>>(X, out, 12, NPIX / 12);
        finalize_kernel<<<(OUT_ELEMS + 255) / 256, 256, 0, stream>>>(out, C);
    }
}